// Round 5
// baseline (181.836 us; speedup 1.0000x reference)
//
#include <hip/hip_runtime.h>
#include <hip/hip_bf16.h>

typedef __bf16 bf16x8 __attribute__((ext_vector_type(8)));
typedef float f32x4 __attribute__((ext_vector_type(4)));
typedef float f32x16 __attribute__((ext_vector_type(16)));
typedef unsigned short u16;
typedef unsigned int u32;
typedef const __attribute__((address_space(1))) u32 gu32;
typedef __attribute__((address_space(3))) u32 lu32;

__device__ __forceinline__ u16 f2bf_rne(float f){
  union { float f; u32 u; } v; v.f = f;
  u32 r = v.u + 0x7fffu + ((v.u >> 16) & 1u);
  return (u16)(r >> 16);
}
__device__ __forceinline__ u32 pack_trunc(float a, float b){
  union { float f; u32 u; } x, y; x.f = a; y.f = b;
  return (x.u >> 16) | (y.u & 0xffff0000u);
}
// async global->LDS, 16B/lane; lds dst wave-uniform, HW adds lane*16
__device__ __forceinline__ void stage16(const u16* g, u16* l){
  __builtin_amdgcn_global_load_lds((gu32*)g, (lu32*)l, 16, 0, 0);
}
// workgroup barrier WITHOUT vmcnt drain (LDS visibility only).
// In-flight global_load_lds prefetches survive the barrier; their completion
// is guaranteed by the compiler-emitted vmcnt wait before the K-register use
// in the NEXT iteration's QK (older loads retire in order).
#define BARRIER_LGKM() asm volatile("s_waitcnt lgkmcnt(0)\n\ts_barrier" ::: "memory")

// ---------------- prep: WcatT[320][256] bf16 = [Wh | Wf | Wg]^T ----------------
__global__ __launch_bounds__(256) void prep_kernel(
    const float* __restrict__ Wf, const float* __restrict__ Wg,
    const float* __restrict__ Wh, u16* __restrict__ WcatT){
  __shared__ float tile[32][33];
  const int tx = threadIdx.x & 31, ty = threadIdx.x >> 5;
  const int k0 = blockIdx.x * 32, n0 = blockIdx.y * 32;
  #pragma unroll
  for (int i = 0; i < 4; ++i){
    int k = k0 + ty + i * 8, n = n0 + tx;
    float v;
    if (n < 256)      v = Wh[k * 256 + n];
    else if (n < 288) v = Wf[k * 32 + (n - 256)];
    else              v = Wg[k * 32 + (n - 288)];
    tile[ty + i * 8][tx] = v;
  }
  __syncthreads();
  #pragma unroll
  for (int i = 0; i < 4; ++i){
    int n = n0 + ty + i * 8, k = k0 + tx;
    WcatT[n * 256 + k] = f2bf_rne(tile[tx][ty + i * 8]);
  }
}

// ---------------- projection: h/f/g via MFMA, 512 thr / 8 waves ----------------
// block = 64 rows; wave = (rowgrp = wave>>1, colhalf = wave&1), 10 cc-tiles each.
__global__ __launch_bounds__(512) void proj_kernel(
    const float* __restrict__ x, const u16* __restrict__ WcatT,
    u16* __restrict__ Qg, u16* __restrict__ Kg, u16* __restrict__ Vfrag)
{
  __shared__ __align__(16) u16 smem[256 * 72];   // 36 KB, two phases
  u16 (*xb)[264] = (u16(*)[264])smem;
  u16 (*Vr)[72]  = (u16(*)[72])smem;

  const int tid = threadIdx.x;
  const int lane = tid & 63, wave = tid >> 6;
  const int L = lane & 15, quad = lane >> 4;
  const int rowgrp = wave >> 1, colhalf = wave & 1;
  const int n0 = blockIdx.x * 64;

  // stage x (64 rows x 256) fp32 -> bf16 LDS
  const float4* xsrc = (const float4*)(x + (size_t)n0 * 256);
  #pragma unroll
  for (int j = 0; j < 8; ++j){
    int idx = j * 512 + tid;
    int row = idx >> 6, col4 = idx & 63;
    float4 v = xsrc[idx];
    u32 p0 = (u32)f2bf_rne(v.x) | ((u32)f2bf_rne(v.y) << 16);
    u32 p1 = (u32)f2bf_rne(v.z) | ((u32)f2bf_rne(v.w) << 16);
    *(uint2*)&xb[row][col4 * 4] = make_uint2(p0, p1);
  }
  __syncthreads();

  f32x4 acc[10];
  #pragma unroll
  for (int cc = 0; cc < 10; ++cc) acc[cc] = (f32x4){0.f, 0.f, 0.f, 0.f};

  #pragma unroll
  for (int kk = 0; kk < 8; ++kk){
    bf16x8 a = *(const bf16x8*)&xb[rowgrp * 16 + L][kk * 32 + quad * 8];
    #pragma unroll
    for (int cc = 0; cc < 10; ++cc){
      int ccg = colhalf * 10 + cc;
      bf16x8 bfr = *(const bf16x8*)(WcatT + (size_t)(ccg * 16 + L) * 256 + kk * 32 + quad * 8);
      acc[cc] = __builtin_amdgcn_mfma_f32_16x16x32_bf16(a, bfr, acc[cc], 0, 0, 0);
    }
  }

  // Qg/Kg: global cc 16..19 (colhalf==1, local 6..9)
  if (colhalf){
    #pragma unroll
    for (int cc = 6; cc < 10; ++cc){
      int ccg = 10 + cc;                                  // 16..19
      u16* dst = (ccg < 18) ? Kg : Qg;                    // K = f, Q = g
      int c = (ccg & 1) * 16 + L;
      #pragma unroll
      for (int r = 0; r < 4; ++r){
        int row = n0 + rowgrp * 16 + quad * 4 + r;
        dst[(size_t)row * 32 + c] = f2bf_rne(acc[cc][r]);
      }
    }
  }

  __syncthreads();   // xb consumed; reuse smem as Vr

  // scatter h (global cc 0..15) into Vr[c][p]
  {
    const int cmax = colhalf ? 6 : 10;
    for (int cc = 0; cc < cmax; ++cc){
      int ccg = colhalf * 10 + cc;
      int c = ccg * 16 + L;
      #pragma unroll
      for (int r = 0; r < 4; ++r){
        int tn = rowgrp * 16 + quad * 4 + r;
        int p  = ((tn & 15) << 2) | (tn >> 4);
        Vr[c][p] = f2bf_rne(acc[cc][r]);
      }
    }
  }
  __syncthreads();

  // coalesced readout: idx = i*512 + tid -> p_hi = idx>>8, c = idx&255
  u16* Vblk = Vfrag + (size_t)blockIdx.x * (256 * 64);
  #pragma unroll
  for (int i = 0; i < 4; ++i){
    int idx = i * 512 + tid;
    *(uint4*)(Vblk + (size_t)idx * 8) = *(const uint4*)&Vr[idx & 255][(idx >> 8) * 8];
  }
}

// ---------------- flash: 128q x 128c blocks, raw barriers, double-buffered V ------
// grid (32 qtiles, 8 = b*2+chalf, 4 splits) x 512 thr (8 waves), 2 blocks/CU.
// Per kt: [stage V(kt+1) -> buf[(kt+1)&1]; prefetch K(kt+1) regs] -> QK(kc regs)
//   -> exp + lsum + P write -> BARRIER_LGKM (P visible; V(kt) already drained by
//   the vmcnt wait before this kt's QK) -> PV (Plds x Vlds[kt&1]) -> BARRIER_LGKM.
__global__ __launch_bounds__(512, 4) void flash_kernel(
    const u16* __restrict__ Qg, const u16* __restrict__ Kg, const u16* __restrict__ Vfrag,
    u16* __restrict__ Opart, float* __restrict__ Lpart)
{
  constexpr float LOG2E = 1.44269504088896340736f;
  constexpr float SH    = -92.33248261689366f;   // -64*log2(e): p = exp(s-64)
  __shared__ __align__(16) u16 Plds[128][72];    // 18432 B
  __shared__ __align__(16) u16 Vlds[2][8192];    // 2 x 16 KB (64k x 128c)

  const int tid = threadIdx.x, lane = tid & 63, wave = tid >> 6;
  const int L = lane & 15, quad = lane >> 4;
  const int m32 = lane & 31, h32 = lane >> 5;
  const int qquad = wave >> 1, chalf2 = wave & 1;
  const int b = blockIdx.y >> 1, chalf = blockIdx.y & 1;
  const int split = blockIdx.z;
  const int qblk = blockIdx.x * 128;

  const u16* Qb = Qg + (size_t)(b * 4096) * 32;
  const u16* Kb = Kg + (size_t)(b * 4096) * 32;
  const u16* Vb = Vfrag + (size_t)b * (64 * 256 * 64);

  const int g0 = split * 16;

  // prologue: stage V(g0) -> buf0; load K(g0) regs
  {
    const u16* vt = Vb + (size_t)g0 * (256 * 64);
    #pragma unroll
    for (int i = 0; i < 2; ++i){
      int c = wave * 2 + i;
      int ph = c >> 1, c64 = c & 1;
      stage16(vt + (size_t)(ph * 256 + chalf * 128 + c64 * 64) * 8 + lane * 8,
              &Vlds[0][(ph * 128 + c64 * 64) * 8]);
    }
  }
  bf16x8 qa = *(const bf16x8*)(Qb + (size_t)(qblk + wave * 16 + L) * 32 + quad * 8);
  const u16* kp0 = Kb + (size_t)(g0 * 64 + L) * 32 + quad * 8;
  bf16x8 kc0 = *(const bf16x8*)(kp0);
  bf16x8 kc1 = *(const bf16x8*)(kp0 + 512);
  bf16x8 kc2 = *(const bf16x8*)(kp0 + 1024);
  bf16x8 kc3 = *(const bf16x8*)(kp0 + 1536);

  f32x16 acc[2];
  #pragma unroll
  for (int ct = 0; ct < 2; ++ct)
    #pragma unroll
    for (int i = 0; i < 16; ++i) acc[ct][i] = 0.f;
  float lsum[4] = {0.f, 0.f, 0.f, 0.f};
  const f32x4 zero = (f32x4){0.f, 0.f, 0.f, 0.f};

  for (int kt = 0; kt < 16; ++kt){
    const int g = g0 + kt;

    // ---- prefetches for kt+1 (drained by next QK's vmcnt wait) ----
    bf16x8 kn0, kn1, kn2, kn3;
    if (kt < 15){
      const u16* vt = Vb + (size_t)(g + 1) * (256 * 64);
      #pragma unroll
      for (int i = 0; i < 2; ++i){
        int c = wave * 2 + i;
        int ph = c >> 1, c64 = c & 1;
        stage16(vt + (size_t)(ph * 256 + chalf * 128 + c64 * 64) * 8 + lane * 8,
                &Vlds[(kt + 1) & 1][(ph * 128 + c64 * 64) * 8]);
      }
      const u16* kpn = Kb + (size_t)((g + 1) * 64 + L) * 32 + quad * 8;
      kn0 = *(const bf16x8*)(kpn);
      kn1 = *(const bf16x8*)(kpn + 512);
      kn2 = *(const bf16x8*)(kpn + 1024);
      kn3 = *(const bf16x8*)(kpn + 1536);
    }

    // ---- QK^T from registers ----
    f32x4 s0 = __builtin_amdgcn_mfma_f32_16x16x32_bf16(qa, kc0, zero, 0, 0, 0);
    f32x4 s1 = __builtin_amdgcn_mfma_f32_16x16x32_bf16(qa, kc1, zero, 0, 0, 0);
    f32x4 s2 = __builtin_amdgcn_mfma_f32_16x16x32_bf16(qa, kc2, zero, 0, 0, 0);
    f32x4 s3 = __builtin_amdgcn_mfma_f32_16x16x32_bf16(qa, kc3, zero, 0, 0, 0);

    // ---- p = exp(s-64); per-lane l partials; packed P store (col' = L*4+j) ----
    #pragma unroll
    for (int r = 0; r < 4; ++r){
      float p0 = exp2f(fmaf(s0[r], LOG2E, SH));
      float p1 = exp2f(fmaf(s1[r], LOG2E, SH));
      float p2 = exp2f(fmaf(s2[r], LOG2E, SH));
      float p3 = exp2f(fmaf(s3[r], LOG2E, SH));
      lsum[r] += (p0 + p1) + (p2 + p3);
      *(uint2*)&Plds[wave * 16 + quad * 4 + r][L * 4] =
          make_uint2(pack_trunc(p0, p1), pack_trunc(p2, p3));
    }

    BARRIER_LGKM();   // b_mid: all P visible; V(kt) staged (drained pre-QK)

    // ---- O += P V (32x32x16); wave covers rows qquad*32+[0,32), cols chalf2*64+[0,64)
    #pragma unroll
    for (int ks = 0; ks < 4; ++ks){
      bf16x8 af = *(const bf16x8*)&Plds[qquad * 32 + m32][ks * 16 + h32 * 8];
      const int vbase = ((ks * 2 + h32) * 128 + chalf2 * 64 + m32) * 8;
      #pragma unroll
      for (int ct = 0; ct < 2; ++ct){
        bf16x8 vf = *(const bf16x8*)&Vlds[kt & 1][vbase + ct * 32 * 8];
        acc[ct] = __builtin_amdgcn_mfma_f32_32x32x16_bf16(af, vf, acc[ct], 0, 0, 0);
      }
    }

    BARRIER_LGKM();   // b_end: PV reads done -> next kt may overwrite Plds

    if (kt < 15){ kc0 = kn0; kc1 = kn1; kc2 = kn2; kc3 = kn3; }
  }

  // ---- epilogue ----
  u16* Ob = Opart + ((size_t)split * 16384 + (size_t)b * 4096 + qblk) * 256;
  #pragma unroll
  for (int ct = 0; ct < 2; ++ct){
    #pragma unroll
    for (int rg = 0; rg < 16; ++rg){
      int row = qquad * 32 + (rg & 3) + 8 * (rg >> 2) + 4 * h32;  // 32x32 C-layout
      int c = chalf * 128 + chalf2 * 64 + ct * 32 + m32;
      Ob[(size_t)row * 256 + c] = (u16)(__float_as_uint(acc[ct][rg]) >> 16);
    }
  }
  // l: reduce the 16 partial sums across the quad's L lanes; chalf==0 writes
  #pragma unroll
  for (int r = 0; r < 4; ++r){
    lsum[r] += __shfl_xor(lsum[r], 1);
    lsum[r] += __shfl_xor(lsum[r], 2);
    lsum[r] += __shfl_xor(lsum[r], 4);
    lsum[r] += __shfl_xor(lsum[r], 8);
  }
  if (chalf == 0 && L == 0){
    float* Lp = Lpart + split * 16384 + b * 4096 + qblk + wave * 16;
    #pragma unroll
    for (int r = 0; r < 4; ++r) Lp[quad * 4 + r] = lsum[r];
  }
}

// ---------------- combine: out = gamma * (sum O_s)/(sum l_s) + x -------------------
// grid 2048 x 256 thr; block = 8 rows, thread = 8 cols (uint4 / float4 vectorized).
__global__ __launch_bounds__(256) void combine_kernel(
    const float* __restrict__ x, const float* __restrict__ gamma,
    const u16* __restrict__ Opart, const float* __restrict__ Lpart,
    float* __restrict__ out)
{
  const int t = threadIdx.x;
  const int row = blockIdx.x * 8 + (t >> 5);
  const int c0 = (t & 31) * 8;
  const size_t base = (size_t)row * 256 + c0;
  float os[8];
  #pragma unroll
  for (int i = 0; i < 8; ++i) os[i] = 0.f;
  float ls = 0.f;
  #pragma unroll
  for (int s = 0; s < 4; ++s){
    ls += Lpart[s * 16384 + row];
    uint4 u = *(const uint4*)(Opart + (size_t)s * 16384 * 256 + base);
    os[0] += __uint_as_float(u.x << 16);
    os[1] += __uint_as_float(u.x & 0xffff0000u);
    os[2] += __uint_as_float(u.y << 16);
    os[3] += __uint_as_float(u.y & 0xffff0000u);
    os[4] += __uint_as_float(u.z << 16);
    os[5] += __uint_as_float(u.z & 0xffff0000u);
    os[6] += __uint_as_float(u.w << 16);
    os[7] += __uint_as_float(u.w & 0xffff0000u);
  }
  const float r = gamma[0] / ls;
  float4 x0 = *(const float4*)(x + base);
  float4 x1 = *(const float4*)(x + base + 4);
  float4 o0, o1;
  o0.x = os[0] * r + x0.x;  o0.y = os[1] * r + x0.y;
  o0.z = os[2] * r + x0.z;  o0.w = os[3] * r + x0.w;
  o1.x = os[4] * r + x1.x;  o1.y = os[5] * r + x1.y;
  o1.z = os[6] * r + x1.z;  o1.w = os[7] * r + x1.w;
  *(float4*)(out + base)     = o0;
  *(float4*)(out + base + 4) = o1;
}

extern "C" void kernel_launch(void* const* d_in, const int* in_sizes, int n_in,
                              void* d_out, int out_size, void* d_ws, size_t ws_size,
                              hipStream_t stream) {
  const float* x     = (const float*)d_in[0];
  const float* Wf    = (const float*)d_in[1];
  const float* Wg    = (const float*)d_in[2];
  const float* Wh    = (const float*)d_in[3];
  const float* gamma = (const float*)d_in[4];
  float* out = (float*)d_out;

  u16* p = (u16*)d_ws;
  u16* Qg    = p;  p += 16384 * 32;               // 1 MB
  u16* Kg    = p;  p += 16384 * 32;               // 1 MB
  u16* Vfrag = p;  p += 4 * 64 * 256 * 64;        // 8 MB, fragment-major
  u16* WcatT = p;  p += 320 * 256;                // 160 KB
  u16* Opart = p;  p += (size_t)4 * 16384 * 256;  // 32 MB
  float* Lpart = (float*)p;                       // 256 KB

  prep_kernel<<<dim3(8, 10), 256, 0, stream>>>(Wf, Wg, Wh, WcatT);
  proj_kernel<<<256, 512, 0, stream>>>(x, WcatT, Qg, Kg, Vfrag);
  flash_kernel<<<dim3(32, 8, 4), 512, 0, stream>>>(Qg, Kg, Vfrag, Opart, Lpart);
  combine_kernel<<<2048, 256, 0, stream>>>(x, gamma, Opart, Lpart, out);
}

// Round 6
// 161.021 us; speedup vs baseline: 1.1293x; 1.1293x over previous
//
#include <hip/hip_runtime.h>
#include <hip/hip_bf16.h>

typedef __bf16 bf16x8 __attribute__((ext_vector_type(8)));
typedef float f32x4 __attribute__((ext_vector_type(4)));
typedef float f32x16 __attribute__((ext_vector_type(16)));
typedef unsigned short u16;
typedef unsigned int u32;
typedef const __attribute__((address_space(1))) u32 gu32;
typedef __attribute__((address_space(3))) u32 lu32;

__device__ __forceinline__ u16 f2bf_rne(float f){
  union { float f; u32 u; } v; v.f = f;
  u32 r = v.u + 0x7fffu + ((v.u >> 16) & 1u);
  return (u16)(r >> 16);
}
// pack hi16(a)|hi16(b)<<16 in ONE v_perm_b32 (truncation; P feeds attention weights)
__device__ __forceinline__ u32 pack2(float a, float b){
  return __builtin_amdgcn_perm(__float_as_uint(a), __float_as_uint(b), 0x03020706u);
}
// async global->LDS, 16B/lane; lds dst wave-uniform, HW adds lane*16
__device__ __forceinline__ void stage16(const u16* g, u16* l){
  __builtin_amdgcn_global_load_lds((gu32*)g, (lu32*)l, 16, 0, 0);
}
// workgroup barrier WITHOUT vmcnt drain (LDS visibility only): in-flight
// global_load_lds / global prefetches ride through.
#define BARRIER_LGKM() asm volatile("s_waitcnt lgkmcnt(0)\n\ts_barrier" ::: "memory")

// ---------------- prep: WcatT[320][256] bf16 = [Wh | Wf | Wg]^T ----------------
__global__ __launch_bounds__(256) void prep_kernel(
    const float* __restrict__ Wf, const float* __restrict__ Wg,
    const float* __restrict__ Wh, u16* __restrict__ WcatT){
  __shared__ float tile[32][33];
  const int tx = threadIdx.x & 31, ty = threadIdx.x >> 5;
  const int k0 = blockIdx.x * 32, n0 = blockIdx.y * 32;
  #pragma unroll
  for (int i = 0; i < 4; ++i){
    int k = k0 + ty + i * 8, n = n0 + tx;
    float v;
    if (n < 256)      v = Wh[k * 256 + n];
    else if (n < 288) v = Wf[k * 32 + (n - 256)];
    else              v = Wg[k * 32 + (n - 288)];
    tile[ty + i * 8][tx] = v;
  }
  __syncthreads();
  #pragma unroll
  for (int i = 0; i < 4; ++i){
    int n = n0 + ty + i * 8, k = k0 + tx;
    WcatT[n * 256 + k] = f2bf_rne(tile[tx][ty + i * 8]);
  }
}

// ---------------- projection: h/f/g via MFMA, 512 thr / 8 waves ----------------
// Qg is pre-scaled by log2(e) so flash's softmax needs no fmaf.
__global__ __launch_bounds__(512) void proj_kernel(
    const float* __restrict__ x, const u16* __restrict__ WcatT,
    u16* __restrict__ Qg, u16* __restrict__ Kg, u16* __restrict__ Vfrag)
{
  __shared__ __align__(16) u16 smem[256 * 72];   // 36 KB, two phases
  u16 (*xb)[264] = (u16(*)[264])smem;
  u16 (*Vr)[72]  = (u16(*)[72])smem;

  const int tid = threadIdx.x;
  const int lane = tid & 63, wave = tid >> 6;
  const int L = lane & 15, quad = lane >> 4;
  const int rowgrp = wave >> 1, colhalf = wave & 1;
  const int n0 = blockIdx.x * 64;

  const float4* xsrc = (const float4*)(x + (size_t)n0 * 256);
  #pragma unroll
  for (int j = 0; j < 8; ++j){
    int idx = j * 512 + tid;
    int row = idx >> 6, col4 = idx & 63;
    float4 v = xsrc[idx];
    u32 p0 = (u32)f2bf_rne(v.x) | ((u32)f2bf_rne(v.y) << 16);
    u32 p1 = (u32)f2bf_rne(v.z) | ((u32)f2bf_rne(v.w) << 16);
    *(uint2*)&xb[row][col4 * 4] = make_uint2(p0, p1);
  }
  __syncthreads();

  f32x4 acc[10];
  #pragma unroll
  for (int cc = 0; cc < 10; ++cc) acc[cc] = (f32x4){0.f, 0.f, 0.f, 0.f};

  #pragma unroll
  for (int kk = 0; kk < 8; ++kk){
    bf16x8 a = *(const bf16x8*)&xb[rowgrp * 16 + L][kk * 32 + quad * 8];
    #pragma unroll
    for (int cc = 0; cc < 10; ++cc){
      int ccg = colhalf * 10 + cc;
      bf16x8 bfr = *(const bf16x8*)(WcatT + (size_t)(ccg * 16 + L) * 256 + kk * 32 + quad * 8);
      acc[cc] = __builtin_amdgcn_mfma_f32_16x16x32_bf16(a, bfr, acc[cc], 0, 0, 0);
    }
  }

  // Qg/Kg: global cc 16..19 (colhalf==1, local 6..9); Qg scaled by log2(e)
  if (colhalf){
    #pragma unroll
    for (int cc = 6; cc < 10; ++cc){
      int ccg = 10 + cc;                                  // 16..19
      u16* dst = (ccg < 18) ? Kg : Qg;                    // K = f, Q = g
      float sc = (ccg < 18) ? 1.0f : 1.44269504088896f;
      int c = (ccg & 1) * 16 + L;
      #pragma unroll
      for (int r = 0; r < 4; ++r){
        int row = n0 + rowgrp * 16 + quad * 4 + r;
        dst[(size_t)row * 32 + c] = f2bf_rne(acc[cc][r] * sc);
      }
    }
  }

  __syncthreads();   // xb consumed; reuse smem as Vr

  {
    const int cmax = colhalf ? 6 : 10;
    for (int cc = 0; cc < cmax; ++cc){
      int ccg = colhalf * 10 + cc;
      int c = ccg * 16 + L;
      #pragma unroll
      for (int r = 0; r < 4; ++r){
        int tn = rowgrp * 16 + quad * 4 + r;
        int p  = ((tn & 15) << 2) | (tn >> 4);
        Vr[c][p] = f2bf_rne(acc[cc][r]);
      }
    }
  }
  __syncthreads();

  u16* Vblk = Vfrag + (size_t)blockIdx.x * (256 * 64);
  #pragma unroll
  for (int i = 0; i < 4; ++i){
    int idx = i * 512 + tid;
    *(uint4*)(Vblk + (size_t)idx * 8) = *(const uint4*)&Vr[idx & 255][(idx >> 8) * 8];
  }
}

// ---------------- flash: 128q x 256c, 8 waves, LDS V, lean softmax ----------------
// grid (32 qtiles, 4 batch, 4 splits) x 512 thr, 2 blocks/CU (50.7 KB LDS).
// Per kt: QK(kc regs) -> p = native_exp2(s+SH), v_perm pack, lsum -> P store
//  -> __syncthreads (b_mid: P visible; vmcnt0 = exactly the V(kt) stage drain,
//     window = previous bottom .. here) -> K(kt+1) reg prefetch -> PV
//  -> BARRIER_LGKM (b_end: no vm drain, K prefetch rides through)
//  -> stage V(kt+1) -> kc=kn (vmcnt retires K, leaves V stages in flight).
__global__ __launch_bounds__(512, 4) void flash_kernel(
    const u16* __restrict__ Qg, const u16* __restrict__ Kg, const u16* __restrict__ Vfrag,
    u16* __restrict__ Opart, float* __restrict__ Lpart)
{
  constexpr float SH = -92.33248261689366f;      // -64*log2(e); s already log2-scaled
  __shared__ __align__(16) u16 Plds[128][72];    // 18432 B
  __shared__ __align__(16) u16 Vlds[16384];      // 32768 B

  const int tid = threadIdx.x, lane = tid & 63, wave = tid >> 6;
  const int L = lane & 15, quad = lane >> 4;
  const int m32 = lane & 31, h32 = lane >> 5;
  const int qquad = wave & 3, chalf = wave >> 2;
  const int b = blockIdx.y, split = blockIdx.z;
  const int qblk = blockIdx.x * 128;

  const u16* Qb = Qg + (size_t)(b * 4096) * 32;
  const u16* Kb = Kg + (size_t)(b * 4096) * 32;
  const u16* Vb = Vfrag + (size_t)b * (64 * 256 * 64);

  const int g0 = split * 16;
  // prologue: stage V(g0) FIRST, then K(g0) loads — in-order vm retirement makes
  // every later K-wait also certify the V stages.
  {
    const u16* vt = Vb + (size_t)g0 * (256 * 64);
    #pragma unroll
    for (int i = 0; i < 4; ++i){
      int chunk = wave * 4 + i;
      stage16(vt + chunk * 512 + lane * 8, &Vlds[chunk * 512]);
    }
  }
  bf16x8 qa = *(const bf16x8*)(Qb + (size_t)(qblk + wave * 16 + L) * 32 + quad * 8);
  const u16* kp0 = Kb + (size_t)(g0 * 64 + L) * 32 + quad * 8;
  bf16x8 kc0 = *(const bf16x8*)(kp0);
  bf16x8 kc1 = *(const bf16x8*)(kp0 + 512);
  bf16x8 kc2 = *(const bf16x8*)(kp0 + 1024);
  bf16x8 kc3 = *(const bf16x8*)(kp0 + 1536);

  f32x16 acc[4];
  #pragma unroll
  for (int ct = 0; ct < 4; ++ct)
    #pragma unroll
    for (int i = 0; i < 16; ++i) acc[ct][i] = 0.f;
  float lsum[4] = {0.f, 0.f, 0.f, 0.f};
  const f32x4 zero = (f32x4){0.f, 0.f, 0.f, 0.f};

  for (int kt = 0; kt < 16; ++kt){
    const int g = g0 + kt;

    // ---- QK^T from registers (s is log2-scaled via Qg) ----
    f32x4 s0 = __builtin_amdgcn_mfma_f32_16x16x32_bf16(qa, kc0, zero, 0, 0, 0);
    f32x4 s1 = __builtin_amdgcn_mfma_f32_16x16x32_bf16(qa, kc1, zero, 0, 0, 0);
    f32x4 s2 = __builtin_amdgcn_mfma_f32_16x16x32_bf16(qa, kc2, zero, 0, 0, 0);
    f32x4 s3 = __builtin_amdgcn_mfma_f32_16x16x32_bf16(qa, kc3, zero, 0, 0, 0);

    // ---- p = exp2(s+SH), native; lsum; packed P store (col' = L*4+j) ----
    #pragma unroll
    for (int r = 0; r < 4; ++r){
      float p0 = __builtin_amdgcn_exp2f(s0[r] + SH);
      float p1 = __builtin_amdgcn_exp2f(s1[r] + SH);
      float p2 = __builtin_amdgcn_exp2f(s2[r] + SH);
      float p3 = __builtin_amdgcn_exp2f(s3[r] + SH);
      lsum[r] += (p0 + p1) + (p2 + p3);
      *(uint2*)&Plds[wave * 16 + quad * 4 + r][L * 4] =
          make_uint2(pack2(p0, p1), pack2(p2, p3));
    }

    __syncthreads();   // b_mid: P visible; vmcnt(0) drains exactly V(kt) stages

    // ---- K(kt+1) register prefetch ----
    bf16x8 kn0, kn1, kn2, kn3;
    if (kt < 15){
      const u16* kpn = Kb + (size_t)((g + 1) * 64 + L) * 32 + quad * 8;
      kn0 = *(const bf16x8*)(kpn);
      kn1 = *(const bf16x8*)(kpn + 512);
      kn2 = *(const bf16x8*)(kpn + 1024);
      kn3 = *(const bf16x8*)(kpn + 1536);
    }

    // ---- O += P V (32x32x16) ----
    #pragma unroll
    for (int ks = 0; ks < 4; ++ks){
      bf16x8 af = *(const bf16x8*)&Plds[qquad * 32 + m32][ks * 16 + h32 * 8];
      const int vbase = ((ks * 2 + h32) * 256 + chalf * 128 + m32) * 8;
      #pragma unroll
      for (int ct = 0; ct < 4; ++ct){
        bf16x8 vf = *(const bf16x8*)&Vlds[vbase + ct * 32 * 8];
        acc[ct] = __builtin_amdgcn_mfma_f32_32x32x16_bf16(af, vf, acc[ct], 0, 0, 0);
      }
    }

    BARRIER_LGKM();    // b_end: PV reads done; K prefetch stays in flight

    if (kt < 15){
      const u16* vt = Vb + (size_t)(g + 1) * (256 * 64);
      #pragma unroll
      for (int i = 0; i < 4; ++i){
        int chunk = wave * 4 + i;
        stage16(vt + chunk * 512 + lane * 8, &Vlds[chunk * 512]);
      }
      // kc=kn use forces vmcnt wait on K loads (older than the V stages just
      // issued) -> V stages remain in flight into the next iteration.
      kc0 = kn0; kc1 = kn1; kc2 = kn2; kc3 = kn3;
    }
  }

  // ---- epilogue: Opart (bf16, unnormalized), Lpart (fp32) ----
  u16* Ob = Opart + ((size_t)split * 16384 + (size_t)b * 4096 + qblk) * 256;
  #pragma unroll
  for (int ct = 0; ct < 4; ++ct){
    #pragma unroll
    for (int rg = 0; rg < 16; ++rg){
      int row = qquad * 32 + (rg & 3) + 8 * (rg >> 2) + 4 * h32;  // 32x32 C-layout
      int c = chalf * 128 + ct * 32 + m32;
      Ob[(size_t)row * 256 + c] = (u16)(__float_as_uint(acc[ct][rg]) >> 16);
    }
  }
  #pragma unroll
  for (int r = 0; r < 4; ++r){
    lsum[r] += __shfl_xor(lsum[r], 1);
    lsum[r] += __shfl_xor(lsum[r], 2);
    lsum[r] += __shfl_xor(lsum[r], 4);
    lsum[r] += __shfl_xor(lsum[r], 8);
  }
  if (L == 0){
    float* Lp = Lpart + split * 16384 + b * 4096 + qblk + wave * 16;
    #pragma unroll
    for (int r = 0; r < 4; ++r) Lp[quad * 4 + r] = lsum[r];
  }
}

// ---------------- combine: out = gamma * (sum O_s)/(sum l_s) + x -------------------
__global__ __launch_bounds__(256) void combine_kernel(
    const float* __restrict__ x, const float* __restrict__ gamma,
    const u16* __restrict__ Opart, const float* __restrict__ Lpart,
    float* __restrict__ out)
{
  const int t = threadIdx.x;
  const int row = blockIdx.x * 8 + (t >> 5);
  const int c0 = (t & 31) * 8;
  const size_t base = (size_t)row * 256 + c0;
  float os[8];
  #pragma unroll
  for (int i = 0; i < 8; ++i) os[i] = 0.f;
  float ls = 0.f;
  #pragma unroll
  for (int s = 0; s < 4; ++s){
    ls += Lpart[s * 16384 + row];
    uint4 u = *(const uint4*)(Opart + (size_t)s * 16384 * 256 + base);
    os[0] += __uint_as_float(u.x << 16);
    os[1] += __uint_as_float(u.x & 0xffff0000u);
    os[2] += __uint_as_float(u.y << 16);
    os[3] += __uint_as_float(u.y & 0xffff0000u);
    os[4] += __uint_as_float(u.z << 16);
    os[5] += __uint_as_float(u.z & 0xffff0000u);
    os[6] += __uint_as_float(u.w << 16);
    os[7] += __uint_as_float(u.w & 0xffff0000u);
  }
  const float r = gamma[0] / ls;
  float4 x0 = *(const float4*)(x + base);
  float4 x1 = *(const float4*)(x + base + 4);
  float4 o0, o1;
  o0.x = os[0] * r + x0.x;  o0.y = os[1] * r + x0.y;
  o0.z = os[2] * r + x0.z;  o0.w = os[3] * r + x0.w;
  o1.x = os[4] * r + x1.x;  o1.y = os[5] * r + x1.y;
  o1.z = os[6] * r + x1.z;  o1.w = os[7] * r + x1.w;
  *(float4*)(out + base)     = o0;
  *(float4*)(out + base + 4) = o1;
}

extern "C" void kernel_launch(void* const* d_in, const int* in_sizes, int n_in,
                              void* d_out, int out_size, void* d_ws, size_t ws_size,
                              hipStream_t stream) {
  const float* x     = (const float*)d_in[0];
  const float* Wf    = (const float*)d_in[1];
  const float* Wg    = (const float*)d_in[2];
  const float* Wh    = (const float*)d_in[3];
  const float* gamma = (const float*)d_in[4];
  float* out = (float*)d_out;

  u16* p = (u16*)d_ws;
  u16* Qg    = p;  p += 16384 * 32;               // 1 MB
  u16* Kg    = p;  p += 16384 * 32;               // 1 MB
  u16* Vfrag = p;  p += 4 * 64 * 256 * 64;        // 8 MB, fragment-major
  u16* WcatT = p;  p += 320 * 256;                // 160 KB
  u16* Opart = p;  p += (size_t)4 * 16384 * 256;  // 32 MB
  float* Lpart = (float*)p;                       // 256 KB

  prep_kernel<<<dim3(8, 10), 256, 0, stream>>>(Wf, Wg, Wh, WcatT);
  proj_kernel<<<256, 512, 0, stream>>>(x, WcatT, Qg, Kg, Vfrag);
  flash_kernel<<<dim3(32, 4, 4), 512, 0, stream>>>(Qg, Kg, Vfrag, Opart, Lpart);
  combine_kernel<<<2048, 256, 0, stream>>>(x, gamma, Opart, Lpart, out);
}